// Round 3
// baseline (156.141 us; speedup 1.0000x reference)
//
#include <hip/hip_runtime.h>
#include <hip/hip_cooperative_groups.h>

namespace cg = cooperative_groups;

#define TSEQ 512
#define HDIM 256
#define NDIM 64
#define LC   64        // conv truncation; ||A||=1/1.1 -> tail ~0.9^64 ~ 2e-3 rel
#define MT   16        // rows (t) per block = MFMA M
#define YSTR 260       // padded f32 LDS row stride
#define NWB  128       // work blocks; block NWB is the W-chain block

typedef __attribute__((ext_vector_type(4))) float  f32x4;
typedef __attribute__((ext_vector_type(8))) short  s16x8;
typedef __attribute__((ext_vector_type(4))) unsigned short u16x4;

__device__ __forceinline__ float wave_red(float v) {
#pragma unroll
    for (int m = 1; m < 64; m <<= 1) v += __shfl_xor(v, m, 64);
    return v;
}
__device__ __forceinline__ float lane_bcast(float v, int lane) {
    return __int_as_float(__builtin_amdgcn_readlane(__float_as_int(v), lane));
}
__device__ __forceinline__ unsigned short f2bf(float f) {
    unsigned u = __float_as_uint(f);
    u += 0x7fffu + ((u >> 16) & 1u);
    return (unsigned short)(u >> 16);
}
__device__ __forceinline__ float bf2f(unsigned short h) {
    return __uint_as_float(((unsigned)h) << 16);
}
// byte offset of 16B chunk `chunk` in row `row` of a [16][256] bf16 LDS tile (XOR swizzle)
__device__ __forceinline__ int swz(int row, int chunk) {
    return row * 512 + (((chunk) ^ (row & 7)) << 4);
}

__global__ void __launch_bounds__(256, 1) k_fused(
    const float* __restrict__ x, const float* __restrict__ Win,
    const float* __restrict__ bin, const float* __restrict__ Wout,
    const float* __restrict__ bout, const float* __restrict__ A,
    const float* __restrict__ Bm, const float* __restrict__ Cm,
    const float* __restrict__ Dm,
    unsigned short* __restrict__ Win_bf, unsigned short* __restrict__ Wout_bf,
    unsigned short* __restrict__ Bm_bf, unsigned short* __restrict__ Dm_bf,
    float* __restrict__ wbuf, float* __restrict__ BiA, float* __restrict__ BiB,
    float* __restrict__ out)
{
    cg::grid_group grid = cg::this_grid();

    __shared__ __align__(16) unsigned short xl[MT * HDIM];   // h tile, bf16 swizzled
    __shared__ __align__(16) float yl[MT * YSTR];            // f32 scratch rows
    __shared__ __align__(16) float bwin[80 * NDIM];          // binp window [t0-64, t0+15]
    __shared__ __align__(16) float wlds[LC * NDIM];          // w_j for current layer
    __shared__ float cfin[MT];

    const int gid = blockIdx.x, tid = threadIdx.x;
    const int lane = tid & 63, wv = tid >> 6;
    const int m = lane & 15, cgq = lane >> 4;
    const f32x4 z4 = {0.f, 0.f, 0.f, 0.f};

    if (gid == NWB) {
        // ---------- W-chain block ----------
        grid.sync();                                   // sync0
        const int l = wv;
        const float* cp = Cm + (size_t)l * HDIM * NDIM + lane;
        float c0 = 0.f, c1 = 0.f, c2 = 0.f, c3 = 0.f;
        for (int h = 0; h < HDIM; h += 4) {
            c0 += cp[(h + 0) * NDIM]; c1 += cp[(h + 1) * NDIM];
            c2 += cp[(h + 2) * NDIM]; c3 += cp[(h + 3) * NDIM];
        }
        float w = ((c0 + c1) + (c2 + c3)) * (1.0f / HDIM);
        float areg[NDIM];
        const float* ap = A + (size_t)l * NDIM * NDIM + lane;
#pragma unroll
        for (int n = 0; n < NDIM; ++n) areg[n] = ap[n * NDIM];
        float* wl = wbuf + (size_t)l * LC * NDIM;
        wl[lane] = w;
        for (int j = 1; j < LC; ++j) {
            float p0 = 0.f, p1 = 0.f, p2 = 0.f, p3 = 0.f;
#pragma unroll
            for (int n = 0; n < NDIM; n += 4) {
                p0 += lane_bcast(w, n + 0) * areg[n + 0];
                p1 += lane_bcast(w, n + 1) * areg[n + 1];
                p2 += lane_bcast(w, n + 2) * areg[n + 2];
                p3 += lane_bcast(w, n + 3) * areg[n + 3];
            }
            w = (p0 + p1) + (p2 + p3);
            wl[j * NDIM + lane] = w;
        }
        grid.sync();                                   // sync1
        grid.sync(); grid.sync(); grid.sync();         // layer 0..2 syncs
        return;
    }

    // ---------- P0: distributed f32->bf16 weight conversion ----------
    {
        const int gthr = gid * 256 + tid;              // 0..32767
        // float4 units: Win 16384 | Wout 16384 | Bm 16384 | Dm 65536 = 114688
        for (int q = gthr; q < 114688; q += NWB * 256) {
            const float* s; unsigned short* d; int off;
            if (q < 16384)      { s = Win;  d = Win_bf;  off = q; }
            else if (q < 32768) { s = Wout; d = Wout_bf; off = q - 16384; }
            else if (q < 49152) { s = Bm;   d = Bm_bf;   off = q - 32768; }
            else                { s = Dm;   d = Dm_bf;   off = q - 49152; }
            f32x4 v = ((const f32x4*)s)[off];
            u16x4 p; p[0] = f2bf(v[0]); p[1] = f2bf(v[1]); p[2] = f2bf(v[2]); p[3] = f2bf(v[3]);
            ((u16x4*)d)[off] = p;
        }
    }

    const int b = gid >> 5, tb = gid & 31, t0 = tb * MT;
    const size_t grow = (size_t)(b * TSEQ + t0);

    // ---------- stage x rows (f32 -> bf16, swizzled) ----------
    {
        const float* gs = x + grow * HDIM;
        for (int q = tid; q < MT * 64; q += 256) {     // 1024 float4
            int row = q >> 6, c4 = q & 63;
            f32x4 v = ((const f32x4*)gs)[q];
            u16x4 p; p[0] = f2bf(v[0]); p[1] = f2bf(v[1]); p[2] = f2bf(v[2]); p[3] = f2bf(v[3]);
            *(u16x4*)((char*)xl + swz(row, c4 >> 1) + (c4 & 1) * 8) = p;
        }
    }
    grid.sync();                                       // sync0 (weights ready; also covers xl)

    // ---------- in-GEMM: h0 = x @ Win^T + bin ----------
    {
        f32x4 acc[4]; acc[0] = z4; acc[1] = z4; acc[2] = z4; acc[3] = z4;
#pragma unroll
        for (int ks = 0; ks < 8; ++ks) {
            s16x8 av = *(const s16x8*)((const char*)xl + swz(m, ks * 4 + cgq));
#pragma unroll
            for (int nt = 0; nt < 4; ++nt) {
                int n = wv * 64 + nt * 16 + m;
                s16x8 bv = *(const s16x8*)(Win_bf + (size_t)n * HDIM + ks * 32 + cgq * 8);
                acc[nt] = __builtin_amdgcn_mfma_f32_16x16x32_bf16(av, bv, acc[nt], 0, 0, 0);
            }
        }
#pragma unroll
        for (int nt = 0; nt < 4; ++nt) {
            int hcol = wv * 64 + nt * 16 + m;
            float bi = bin[hcol];
#pragma unroll
            for (int reg = 0; reg < 4; ++reg)
                yl[(cgq * 4 + reg) * YSTR + hcol] = acc[nt][reg] + bi;
        }
    }
    __syncthreads();
    // pack h0 rows -> xl (bf16 swizzled); h stays in LDS for all layers
#pragma unroll
    for (int q = 0; q < 4; ++q) {
        int r = wv * 4 + q;
        f32x4 yv = *(const f32x4*)(yl + r * YSTR + lane * 4);
        u16x4 zp; zp[0] = f2bf(yv[0]); zp[1] = f2bf(yv[1]); zp[2] = f2bf(yv[2]); zp[3] = f2bf(yv[3]);
        *(u16x4*)((char*)xl + swz(r, lane >> 1) + (lane & 1) * 8) = zp;
    }
    __syncthreads();
    // B-proj layer 0 -> BiA
    {
        f32x4 accb = z4;
        const int n0 = wv * 16;
#pragma unroll
        for (int ks = 0; ks < 8; ++ks) {
            s16x8 av = *(const s16x8*)((const char*)xl + swz(m, ks * 4 + cgq));
            s16x8 bv = *(const s16x8*)(Bm_bf + (size_t)(n0 + m) * HDIM + ks * 32 + cgq * 8);
            accb = __builtin_amdgcn_mfma_f32_16x16x32_bf16(av, bv, accb, 0, 0, 0);
        }
#pragma unroll
        for (int reg = 0; reg < 4; ++reg)
            BiA[(grow + cgq * 4 + reg) * NDIM + n0 + m] = accb[reg];
    }
    grid.sync();                                       // sync1 (binp0 + wbuf ready)

    // ---------- layer loop ----------
#pragma unroll 1
    for (int l = 0; l < 4; ++l) {
        const float* wl = wbuf + (size_t)l * LC * NDIM;
        const float* bi = (l & 1) ? BiB : BiA;
        float*       bo = (l & 1) ? BiA : BiB;
        const unsigned short* Dl = Dm_bf + (size_t)l * HDIM * HDIM;

        // stage w (1024 f4) + binp window (1280 f4) into LDS
        for (int q = tid; q < LC * NDIM / 4; q += 256)
            ((f32x4*)wlds)[q] = ((const f32x4*)wl)[q];
        {
            const float* bb = bi + (size_t)b * TSEQ * NDIM;
            for (int q = tid; q < 80 * 16; q += 256) {
                int r = q >> 4, c4 = q & 15;
                int t = t0 - 64 + r;
                f32x4 v = (t >= 0) ? ((const f32x4*)(bb + (size_t)t * NDIM))[c4] : z4;
                ((f32x4*)bwin)[q] = v;
            }
        }
        __syncthreads();

        // conv: c[t] = sum_{j<64} w_j . binp[t-1-j]   (rows from LDS, static unrolled)
        {
            const int r0 = wv * 4;
            float c0 = 0.f, c1 = 0.f, c2 = 0.f, c3 = 0.f;
            float v0 = bwin[(63 + r0) * NDIM + lane];
            float v1 = bwin[(64 + r0) * NDIM + lane];
            float v2 = bwin[(65 + r0) * NDIM + lane];
            float v3 = bwin[(66 + r0) * NDIM + lane];
#pragma unroll
            for (int j = 0; j < LC; ++j) {
                float wj = wlds[j * NDIM + lane];
                c0 += wj * v0; c1 += wj * v1; c2 += wj * v2; c3 += wj * v3;
                v3 = v2; v2 = v1; v1 = v0;
                int nr = 62 + r0 - j; nr = nr < 0 ? 0 : nr;
                v0 = bwin[nr * NDIM + lane];
            }
            c0 = wave_red(c0); c1 = wave_red(c1); c2 = wave_red(c2); c3 = wave_red(c3);
            if (lane == 0) { cfin[r0] = c0; cfin[r0 + 1] = c1; cfin[r0 + 2] = c2; cfin[r0 + 3] = c3; }
        }
        __syncthreads();

        // D-GEMM + c + gelu + residual -> yl
        {
            f32x4 acc[4]; acc[0] = z4; acc[1] = z4; acc[2] = z4; acc[3] = z4;
#pragma unroll
            for (int ks = 0; ks < 8; ++ks) {
                s16x8 av = *(const s16x8*)((const char*)xl + swz(m, ks * 4 + cgq));
#pragma unroll
                for (int nt = 0; nt < 4; ++nt) {
                    int n = wv * 64 + nt * 16 + m;
                    s16x8 bv = *(const s16x8*)(Dl + (size_t)n * HDIM + ks * 32 + cgq * 8);
                    acc[nt] = __builtin_amdgcn_mfma_f32_16x16x32_bf16(av, bv, acc[nt], 0, 0, 0);
                }
            }
#pragma unroll
            for (int nt = 0; nt < 4; ++nt) {
                int hcol = wv * 64 + nt * 16 + m;
#pragma unroll
                for (int reg = 0; reg < 4; ++reg) {
                    int trow = cgq * 4 + reg;
                    float val = acc[nt][reg] + cfin[trow];
                    float g = 0.5f * val * (1.0f + erff(val * 0.70710678118654752f));
                    int byteo = swz(trow, hcol >> 3) + (hcol & 7) * 2;
                    float r = bf2f(*(const unsigned short*)((const char*)xl + byteo));
                    yl[trow * YSTR + hcol] = g + r;
                }
            }
        }
        __syncthreads();

        // LayerNorm (analytically fused double-LN when l==3) -> xl
        {
            const bool last = (l == 3);
#pragma unroll
            for (int q = 0; q < 4; ++q) {
                int r = wv * 4 + q;
                f32x4 yv = *(const f32x4*)(yl + r * YSTR + lane * 4);
                float s = (yv[0] + yv[1]) + (yv[2] + yv[3]);
                float sq = yv[0] * yv[0] + yv[1] * yv[1] + yv[2] * yv[2] + yv[3] * yv[3];
                s = wave_red(s); sq = wave_red(sq);
                float mn = s * (1.0f / HDIM);
                float var = sq * (1.0f / HDIM) - mn * mn;
                float rs = rsqrtf(var + 1e-5f);
                if (last) { float vz = var * rs * rs; rs = rs * rsqrtf(vz + 1e-5f); }
                u16x4 zp;
                zp[0] = f2bf((yv[0] - mn) * rs); zp[1] = f2bf((yv[1] - mn) * rs);
                zp[2] = f2bf((yv[2] - mn) * rs); zp[3] = f2bf((yv[3] - mn) * rs);
                *(u16x4*)((char*)xl + swz(r, lane >> 1) + (lane & 1) * 8) = zp;
            }
        }
        __syncthreads();

        if (l < 3) {
            // B-proj for next layer -> bo
            f32x4 accb = z4;
            const unsigned short* Bn = Bm_bf + (size_t)(l + 1) * NDIM * HDIM;
            const int n0 = wv * 16;
#pragma unroll
            for (int ks = 0; ks < 8; ++ks) {
                s16x8 av = *(const s16x8*)((const char*)xl + swz(m, ks * 4 + cgq));
                s16x8 bv = *(const s16x8*)(Bn + (size_t)(n0 + m) * HDIM + ks * 32 + cgq * 8);
                accb = __builtin_amdgcn_mfma_f32_16x16x32_bf16(av, bv, accb, 0, 0, 0);
            }
#pragma unroll
            for (int reg = 0; reg < 4; ++reg)
                bo[(grow + cgq * 4 + reg) * NDIM + n0 + m] = accb[reg];
            grid.sync();                               // binp ready for next layer
        } else {
            // out-GEMM: out = z2 @ Wout^T + bout
            f32x4 a2[4]; a2[0] = z4; a2[1] = z4; a2[2] = z4; a2[3] = z4;
#pragma unroll
            for (int ks = 0; ks < 8; ++ks) {
                s16x8 av = *(const s16x8*)((const char*)xl + swz(m, ks * 4 + cgq));
#pragma unroll
                for (int nt = 0; nt < 4; ++nt) {
                    int n = wv * 64 + nt * 16 + m;
                    s16x8 bv = *(const s16x8*)(Wout_bf + (size_t)n * HDIM + ks * 32 + cgq * 8);
                    a2[nt] = __builtin_amdgcn_mfma_f32_16x16x32_bf16(av, bv, a2[nt], 0, 0, 0);
                }
            }
#pragma unroll
            for (int nt = 0; nt < 4; ++nt) {
                int hcol = wv * 64 + nt * 16 + m;
                float bo2 = bout[hcol];
#pragma unroll
                for (int reg = 0; reg < 4; ++reg)
                    out[(grow + cgq * 4 + reg) * HDIM + hcol] = a2[nt][reg] + bo2;
            }
        }
    }
}

extern "C" void kernel_launch(void* const* d_in, const int* in_sizes, int n_in,
                              void* d_out, int out_size, void* d_ws, size_t ws_size,
                              hipStream_t stream) {
    (void)in_sizes; (void)n_in; (void)out_size; (void)ws_size;
    const float* x    = (const float*)d_in[0];
    const float* Win  = (const float*)d_in[1];
    const float* bin  = (const float*)d_in[2];
    const float* Wout = (const float*)d_in[3];
    const float* bout = (const float*)d_in[4];
    const float* A    = (const float*)d_in[5];
    const float* Bm   = (const float*)d_in[6];
    const float* Cm   = (const float*)d_in[7];
    const float* Dm   = (const float*)d_in[8];

    float* ws = (float*)d_ws;
    float* wbuf = ws;                                          // 4*64*64 f32
    unsigned short* Win_bf  = (unsigned short*)(ws + 16384);   // 65536
    unsigned short* Wout_bf = Win_bf + 65536;
    unsigned short* Bm_bf   = Wout_bf + 65536;
    unsigned short* Dm_bf   = Bm_bf + 65536;                   // 262144
    float* BiA = (float*)(Dm_bf + 262144);                     // 131072 f32
    float* BiB = BiA + 131072;
    float* out = (float*)d_out;

    void* args[] = {
        (void*)&x, (void*)&Win, (void*)&bin, (void*)&Wout, (void*)&bout,
        (void*)&A, (void*)&Bm, (void*)&Cm, (void*)&Dm,
        (void*)&Win_bf, (void*)&Wout_bf, (void*)&Bm_bf, (void*)&Dm_bf,
        (void*)&wbuf, (void*)&BiA, (void*)&BiB, (void*)&out
    };
    hipLaunchCooperativeKernel((const void*)k_fused, dim3(NWB + 1), dim3(256),
                               args, 0, stream);
}

// Round 4
// 105.264 us; speedup vs baseline: 1.4833x; 1.4833x over previous
//
#include <hip/hip_runtime.h>

#define TSEQ 512
#define HDIM 256
#define NDIM 64
#define LC   64        // conv truncation; ||A||=1/1.1 -> tail ~0.9^64 ~ 2e-3 rel
#define MT   16        // rows (t) per block = MFMA M
#define YSTR 260       // padded f32 LDS row stride
#define NWB  128       // work blocks; block NWB is the W-chain block

typedef __attribute__((ext_vector_type(4))) float  f32x4;
typedef __attribute__((ext_vector_type(8))) short  s16x8;
typedef __attribute__((ext_vector_type(4))) unsigned short u16x4;

__device__ __forceinline__ float wave_red(float v) {
#pragma unroll
    for (int m = 1; m < 64; m <<= 1) v += __shfl_xor(v, m, 64);
    return v;
}
__device__ __forceinline__ float lane_bcast(float v, int lane) {
    return __int_as_float(__builtin_amdgcn_readlane(__float_as_int(v), lane));
}
__device__ __forceinline__ unsigned short f2bf(float f) {
    unsigned u = __float_as_uint(f);
    u += 0x7fffu + ((u >> 16) & 1u);
    return (unsigned short)(u >> 16);
}
__device__ __forceinline__ float bf2f(unsigned short h) {
    return __uint_as_float(((unsigned)h) << 16);
}
// byte offset of 16B chunk `chunk` in row `row` of a [16][256] bf16 LDS tile (XOR swizzle)
__device__ __forceinline__ int swz(int row, int chunk) {
    return row * 512 + (((chunk) ^ (row & 7)) << 4);
}

// flags[0..3]   : wbuf ready for layer l
// flags[4 + l*128 + gid] : binp^l tile gid ready
__device__ __forceinline__ void flag_set(unsigned* f, unsigned v) {
    __hip_atomic_store(f, v, __ATOMIC_RELEASE, __HIP_MEMORY_SCOPE_AGENT);
}
__device__ __forceinline__ void flag_wait(const unsigned* f) {
    while (__hip_atomic_load(f, __ATOMIC_ACQUIRE, __HIP_MEMORY_SCOPE_AGENT) == 0u)
        __builtin_amdgcn_s_sleep(2);
}

// ---------------- prep: weight f32->bf16 + flag zeroing ----------------
__global__ void __launch_bounds__(256) k_prep(
    const float* __restrict__ Win, const float* __restrict__ Wout,
    const float* __restrict__ Bm, const float* __restrict__ Dm,
    unsigned short* __restrict__ Win_bf, unsigned short* __restrict__ Wout_bf,
    unsigned short* __restrict__ Bm_bf, unsigned short* __restrict__ Dm_bf,
    unsigned* __restrict__ flags)
{
    const int gid = blockIdx.x, tid = threadIdx.x;
    if (gid == 0) {
        for (int i = tid; i < 4 + 4 * NWB; i += 256) flags[i] = 0u;
    }
    // float4 units: Win 16384 | Wout 16384 | Bm 16384 | Dm 65536 = 114688
    for (int q = gid * 256 + tid; q < 114688; q += 128 * 256) {
        const float* s; unsigned short* d; int off;
        if (q < 16384)      { s = Win;  d = Win_bf;  off = q; }
        else if (q < 32768) { s = Wout; d = Wout_bf; off = q - 16384; }
        else if (q < 49152) { s = Bm;   d = Bm_bf;   off = q - 32768; }
        else                { s = Dm;   d = Dm_bf;   off = q - 49152; }
        f32x4 v = ((const f32x4*)s)[off];
        u16x4 p; p[0] = f2bf(v[0]); p[1] = f2bf(v[1]); p[2] = f2bf(v[2]); p[3] = f2bf(v[3]);
        ((u16x4*)d)[off] = p;
    }
}

// ---------------- fused main ----------------
__global__ void __launch_bounds__(256, 1) k_fused(
    const float* __restrict__ x, const float* __restrict__ bin,
    const float* __restrict__ bout, const float* __restrict__ A,
    const float* __restrict__ Cm,
    const unsigned short* __restrict__ Win_bf, const unsigned short* __restrict__ Wout_bf,
    const unsigned short* __restrict__ Bm_bf, const unsigned short* __restrict__ Dm_bf,
    float* __restrict__ wbuf, float* __restrict__ BiA, float* __restrict__ BiB,
    unsigned* __restrict__ flags, float* __restrict__ out)
{
    __shared__ __align__(16) unsigned short xl[MT * HDIM];   // h tile, bf16 swizzled
    __shared__ __align__(16) float yl[MT * YSTR];            // f32 scratch rows
    __shared__ __align__(16) float bwin[80 * NDIM];          // binp window [t0-64, t0+15]
    __shared__ __align__(16) float wlds[LC * NDIM];          // w_j for current layer
    __shared__ float cfin[MT];

    const int gid = blockIdx.x, tid = threadIdx.x;
    const int lane = tid & 63, wv = tid >> 6;
    const int m = lane & 15, cgq = lane >> 4;
    const f32x4 z4 = {0.f, 0.f, 0.f, 0.f};

    if (gid == NWB) {
        // ---------- W-chain block: w_j = Cbar^T A^j, wave per layer ----------
        const int l = wv;
        const float* cp = Cm + (size_t)l * HDIM * NDIM + lane;
        float c0 = 0.f, c1 = 0.f, c2 = 0.f, c3 = 0.f;
        for (int h = 0; h < HDIM; h += 4) {
            c0 += cp[(h + 0) * NDIM]; c1 += cp[(h + 1) * NDIM];
            c2 += cp[(h + 2) * NDIM]; c3 += cp[(h + 3) * NDIM];
        }
        float w = ((c0 + c1) + (c2 + c3)) * (1.0f / HDIM);
        float areg[NDIM];
        const float* ap = A + (size_t)l * NDIM * NDIM + lane;
#pragma unroll
        for (int n = 0; n < NDIM; ++n) areg[n] = ap[n * NDIM];
        float* wl = wbuf + (size_t)l * LC * NDIM;
        wl[lane] = w;
        for (int j = 1; j < LC; ++j) {
            float p0 = 0.f, p1 = 0.f, p2 = 0.f, p3 = 0.f;
#pragma unroll
            for (int n = 0; n < NDIM; n += 4) {
                p0 += lane_bcast(w, n + 0) * areg[n + 0];
                p1 += lane_bcast(w, n + 1) * areg[n + 1];
                p2 += lane_bcast(w, n + 2) * areg[n + 2];
                p3 += lane_bcast(w, n + 3) * areg[n + 3];
            }
            w = (p0 + p1) + (p2 + p3);
            wl[j * NDIM + lane] = w;
        }
        __threadfence();
        if (lane == 0) flag_set(&flags[l], 1u);
        return;
    }

    const int b = gid >> 5, tb = gid & 31, t0 = tb * MT;
    const size_t grow = (size_t)(b * TSEQ + t0);

    // ---------- stage x rows (f32 -> bf16, swizzled) ----------
    {
        const float* gs = x + grow * HDIM;
        for (int q = tid; q < MT * 64; q += 256) {     // 1024 float4
            int row = q >> 6, c4 = q & 63;
            f32x4 v = ((const f32x4*)gs)[q];
            u16x4 p; p[0] = f2bf(v[0]); p[1] = f2bf(v[1]); p[2] = f2bf(v[2]); p[3] = f2bf(v[3]);
            *(u16x4*)((char*)xl + swz(row, c4 >> 1) + (c4 & 1) * 8) = p;
        }
    }
    __syncthreads();

    // ---------- in-GEMM: h0 = x @ Win^T + bin ----------
    {
        f32x4 acc[4]; acc[0] = z4; acc[1] = z4; acc[2] = z4; acc[3] = z4;
#pragma unroll
        for (int ks = 0; ks < 8; ++ks) {
            s16x8 av = *(const s16x8*)((const char*)xl + swz(m, ks * 4 + cgq));
#pragma unroll
            for (int nt = 0; nt < 4; ++nt) {
                int n = wv * 64 + nt * 16 + m;
                s16x8 bv = *(const s16x8*)(Win_bf + (size_t)n * HDIM + ks * 32 + cgq * 8);
                acc[nt] = __builtin_amdgcn_mfma_f32_16x16x32_bf16(av, bv, acc[nt], 0, 0, 0);
            }
        }
#pragma unroll
        for (int nt = 0; nt < 4; ++nt) {
            int hcol = wv * 64 + nt * 16 + m;
            float bi = bin[hcol];
#pragma unroll
            for (int reg = 0; reg < 4; ++reg)
                yl[(cgq * 4 + reg) * YSTR + hcol] = acc[nt][reg] + bi;
        }
    }
    __syncthreads();
    // pack h0 rows -> xl (bf16 swizzled); h stays in LDS for all layers
#pragma unroll
    for (int q = 0; q < 4; ++q) {
        int r = wv * 4 + q;
        f32x4 yv = *(const f32x4*)(yl + r * YSTR + lane * 4);
        u16x4 zp; zp[0] = f2bf(yv[0]); zp[1] = f2bf(yv[1]); zp[2] = f2bf(yv[2]); zp[3] = f2bf(yv[3]);
        *(u16x4*)((char*)xl + swz(r, lane >> 1) + (lane & 1) * 8) = zp;
    }
    __syncthreads();
    // B-proj layer 0 -> BiA
    {
        f32x4 accb = z4;
        const int n0 = wv * 16;
#pragma unroll
        for (int ks = 0; ks < 8; ++ks) {
            s16x8 av = *(const s16x8*)((const char*)xl + swz(m, ks * 4 + cgq));
            s16x8 bv = *(const s16x8*)(Bm_bf + (size_t)(n0 + m) * HDIM + ks * 32 + cgq * 8);
            accb = __builtin_amdgcn_mfma_f32_16x16x32_bf16(av, bv, accb, 0, 0, 0);
        }
#pragma unroll
        for (int reg = 0; reg < 4; ++reg)
            BiA[(grow + cgq * 4 + reg) * NDIM + n0 + m] = accb[reg];
    }
    __syncthreads();
    if (tid == 0) { __threadfence(); flag_set(&flags[4 + 0 * NWB + gid], 1u); }

    // ---------- layer loop ----------
#pragma unroll 1
    for (int l = 0; l < 4; ++l) {
        const float* wl = wbuf + (size_t)l * LC * NDIM;
        const float* bi = (l & 1) ? BiB : BiA;
        float*       bo = (l & 1) ? BiA : BiB;
        const unsigned short* Dl = Dm_bf + (size_t)l * HDIM * HDIM;

        // ---- wait: w ready (tid 4), neighbor binp tiles tb-1..tb-4 (tid 0..3) ----
        if (tid < 5) {
            const unsigned* fp; bool need;
            if (tid == 4) { fp = &flags[l]; need = true; }
            else          { need = (tb - 1 - tid) >= 0; fp = &flags[4 + l * NWB + gid - 1 - tid]; }
            if (need) flag_wait(fp);
        }
        __syncthreads();

        // stage w (1024 f4) + binp window (1280 f4) into LDS
        for (int q = tid; q < LC * NDIM / 4; q += 256)
            ((f32x4*)wlds)[q] = ((const f32x4*)wl)[q];
        {
            const float* bb = bi + (size_t)b * TSEQ * NDIM;
            for (int q = tid; q < 80 * 16; q += 256) {
                int r = q >> 4, c4 = q & 15;
                int t = t0 - 64 + r;
                f32x4 v = (t >= 0) ? ((const f32x4*)(bb + (size_t)t * NDIM))[c4] : z4;
                ((f32x4*)bwin)[q] = v;
            }
        }
        __syncthreads();

        // conv: c[t] = sum_{j<64} w_j . binp[t-1-j]   (rows from LDS, static unrolled)
        {
            const int r0 = wv * 4;
            float c0 = 0.f, c1 = 0.f, c2 = 0.f, c3 = 0.f;
            float v0 = bwin[(63 + r0) * NDIM + lane];
            float v1 = bwin[(64 + r0) * NDIM + lane];
            float v2 = bwin[(65 + r0) * NDIM + lane];
            float v3 = bwin[(66 + r0) * NDIM + lane];
#pragma unroll
            for (int j = 0; j < LC; ++j) {
                float wj = wlds[j * NDIM + lane];
                c0 += wj * v0; c1 += wj * v1; c2 += wj * v2; c3 += wj * v3;
                v3 = v2; v2 = v1; v1 = v0;
                int nr = 62 + r0 - j; nr = nr < 0 ? 0 : nr;
                v0 = bwin[nr * NDIM + lane];
            }
            c0 = wave_red(c0); c1 = wave_red(c1); c2 = wave_red(c2); c3 = wave_red(c3);
            if (lane == 0) { cfin[r0] = c0; cfin[r0 + 1] = c1; cfin[r0 + 2] = c2; cfin[r0 + 3] = c3; }
        }
        __syncthreads();

        // D-GEMM + c + gelu + residual -> yl
        {
            f32x4 acc[4]; acc[0] = z4; acc[1] = z4; acc[2] = z4; acc[3] = z4;
#pragma unroll
            for (int ks = 0; ks < 8; ++ks) {
                s16x8 av = *(const s16x8*)((const char*)xl + swz(m, ks * 4 + cgq));
#pragma unroll
                for (int nt = 0; nt < 4; ++nt) {
                    int n = wv * 64 + nt * 16 + m;
                    s16x8 bv = *(const s16x8*)(Dl + (size_t)n * HDIM + ks * 32 + cgq * 8);
                    acc[nt] = __builtin_amdgcn_mfma_f32_16x16x32_bf16(av, bv, acc[nt], 0, 0, 0);
                }
            }
#pragma unroll
            for (int nt = 0; nt < 4; ++nt) {
                int hcol = wv * 64 + nt * 16 + m;
#pragma unroll
                for (int reg = 0; reg < 4; ++reg) {
                    int trow = cgq * 4 + reg;
                    float val = acc[nt][reg] + cfin[trow];
                    float g = 0.5f * val * (1.0f + erff(val * 0.70710678118654752f));
                    int byteo = swz(trow, hcol >> 3) + (hcol & 7) * 2;
                    float r = bf2f(*(const unsigned short*)((const char*)xl + byteo));
                    yl[trow * YSTR + hcol] = g + r;
                }
            }
        }
        __syncthreads();

        // LayerNorm (analytically fused double-LN when l==3) -> xl
        {
            const bool last = (l == 3);
#pragma unroll
            for (int q = 0; q < 4; ++q) {
                int r = wv * 4 + q;
                f32x4 yv = *(const f32x4*)(yl + r * YSTR + lane * 4);
                float s = (yv[0] + yv[1]) + (yv[2] + yv[3]);
                float sq = yv[0] * yv[0] + yv[1] * yv[1] + yv[2] * yv[2] + yv[3] * yv[3];
                s = wave_red(s); sq = wave_red(sq);
                float mn = s * (1.0f / HDIM);
                float var = sq * (1.0f / HDIM) - mn * mn;
                float rs = rsqrtf(var + 1e-5f);
                if (last) { float vz = var * rs * rs; rs = rs * rsqrtf(vz + 1e-5f); }
                u16x4 zp;
                zp[0] = f2bf((yv[0] - mn) * rs); zp[1] = f2bf((yv[1] - mn) * rs);
                zp[2] = f2bf((yv[2] - mn) * rs); zp[3] = f2bf((yv[3] - mn) * rs);
                *(u16x4*)((char*)xl + swz(r, lane >> 1) + (lane & 1) * 8) = zp;
            }
        }
        __syncthreads();

        if (l < 3) {
            // B-proj for next layer -> bo
            f32x4 accb = z4;
            const unsigned short* Bn = Bm_bf + (size_t)(l + 1) * NDIM * HDIM;
            const int n0 = wv * 16;
#pragma unroll
            for (int ks = 0; ks < 8; ++ks) {
                s16x8 av = *(const s16x8*)((const char*)xl + swz(m, ks * 4 + cgq));
                s16x8 bv = *(const s16x8*)(Bn + (size_t)(n0 + m) * HDIM + ks * 32 + cgq * 8);
                accb = __builtin_amdgcn_mfma_f32_16x16x32_bf16(av, bv, accb, 0, 0, 0);
            }
#pragma unroll
            for (int reg = 0; reg < 4; ++reg)
                bo[(grow + cgq * 4 + reg) * NDIM + n0 + m] = accb[reg];
            __syncthreads();
            if (tid == 0) { __threadfence(); flag_set(&flags[4 + (l + 1) * NWB + gid], 1u); }
        } else {
            // out-GEMM: out = z2 @ Wout^T + bout
            f32x4 a2[4]; a2[0] = z4; a2[1] = z4; a2[2] = z4; a2[3] = z4;
#pragma unroll
            for (int ks = 0; ks < 8; ++ks) {
                s16x8 av = *(const s16x8*)((const char*)xl + swz(m, ks * 4 + cgq));
#pragma unroll
                for (int nt = 0; nt < 4; ++nt) {
                    int n = wv * 64 + nt * 16 + m;
                    s16x8 bv = *(const s16x8*)(Wout_bf + (size_t)n * HDIM + ks * 32 + cgq * 8);
                    a2[nt] = __builtin_amdgcn_mfma_f32_16x16x32_bf16(av, bv, a2[nt], 0, 0, 0);
                }
            }
#pragma unroll
            for (int nt = 0; nt < 4; ++nt) {
                int hcol = wv * 64 + nt * 16 + m;
                float bo2 = bout[hcol];
#pragma unroll
                for (int reg = 0; reg < 4; ++reg)
                    out[(grow + cgq * 4 + reg) * HDIM + hcol] = a2[nt][reg] + bo2;
            }
        }
    }
}

extern "C" void kernel_launch(void* const* d_in, const int* in_sizes, int n_in,
                              void* d_out, int out_size, void* d_ws, size_t ws_size,
                              hipStream_t stream) {
    (void)in_sizes; (void)n_in; (void)out_size; (void)ws_size;
    const float* x    = (const float*)d_in[0];
    const float* Win  = (const float*)d_in[1];
    const float* bin  = (const float*)d_in[2];
    const float* Wout = (const float*)d_in[3];
    const float* bout = (const float*)d_in[4];
    const float* A    = (const float*)d_in[5];
    const float* Bm   = (const float*)d_in[6];
    const float* Cm   = (const float*)d_in[7];
    const float* Dm   = (const float*)d_in[8];

    float* ws = (float*)d_ws;
    float* wbuf = ws;                                          // [0, 16384)
    unsigned short* Win_bf  = (unsigned short*)(ws + 16384);   // 65536 bf16
    unsigned short* Wout_bf = Win_bf + 65536;
    unsigned short* Bm_bf   = Wout_bf + 65536;
    unsigned short* Dm_bf   = Bm_bf + 65536;                   // 262144 bf16
    float* BiA = (float*)(Dm_bf + 262144);                     // 131072 f32
    float* BiB = BiA + 131072;
    unsigned* flags = (unsigned*)(BiB + 131072);               // 516 u32
    float* out = (float*)d_out;

    k_prep<<<128, 256, 0, stream>>>(Win, Wout, Bm, Dm,
                                    Win_bf, Wout_bf, Bm_bf, Dm_bf, flags);
    k_fused<<<NWB + 1, 256, 0, stream>>>(x, bin, bout, A, Cm,
                                         Win_bf, Wout_bf, Bm_bf, Dm_bf,
                                         wbuf, BiA, BiB, flags, out);
}